// Round 9
// baseline (20178.793 us; speedup 1.0000x reference)
//
#include <hip/hip_runtime.h>
#include <math.h>

#define NN 5184
#define MM 81
#define MP 84
#define BTOT 512
#define NITER 100
#define ITEMS 4
#define THREADS 1024
#define NWG (BTOT/ITEMS)      // 128 workgroups, fully independent
#define YPAD 5188             // y row pad (item stride; 5188%32=4 banks apart)
#define UPAD 88
#define RMAXA 6               // wave 0: 6 rows/thread, waves 1..15: 5
#define NBW 324               // rows per wave in Phase B (5184/16)
// LDS: yL[4][5188] + zL[81][4] + xL[81][4] + uL[4][88]
#define LDS_FLOATS (ITEMS*YPAD + MM*ITEMS*2 + ITEMS*UPAD)
#define LDS_BYTES (LDS_FLOATS*4)   // 87,008 B -> 1 WG/CU

// d_ws: matT[81][5184] fp32 = 1.68 MB (ws proven >= 10.7 MB in round 7)

__global__ void prep(const float* __restrict__ mat, float* __restrict__ matT) {
    int i = blockIdx.x * 256 + threadIdx.x;     // over NN*MM
    if (i >= NN * MM) return;
    int n = i / MM, m = i - n * MM;
    matT[(size_t)m * NN + n] = mat[i];
}

__global__ __launch_bounds__(THREADS) void fista(
        const float* __restrict__ x, const float* __restrict__ lam,
        const float* __restrict__ matT, float* __restrict__ out) {
    extern __shared__ float sm[];
    float* yL = sm;                       // [ITEMS][YPAD]
    float* zL = sm + ITEMS * YPAD;        // [MM][ITEMS]  (float4 per m)
    float* xL = zL + MM * ITEMS;          // [MM][ITEMS]
    float* uL = xL + MM * ITEMS;          // [ITEMS][UPAD]

    const int tid = threadIdx.x;
    const int wv = tid >> 6, lane = tid & 63;
    const int b0 = blockIdx.x * ITEMS;
    const float thr = lam[0];             // lam / MU, MU = 1

    // ---- init: xL/zL = x (transposed to [m][item]), uL = 0 ----
    for (int i = tid; i < MM * ITEMS; i += THREADS) {
        int m = i >> 2, item = i & 3;
        float v = x[(size_t)(b0 + item) * MM + m];
        xL[i] = v; zL[i] = v;
    }
    for (int i = tid; i < ITEMS * UPAD; i += THREADS) uL[i] = 0.f;

    // Phase A row ownership: n = r*1024 + tid (r=5 only for wave 0)
    const int rcnt = (wv == 0) ? 6 : 5;
    // Phase B lane mapping: item x m-quintet (q=15 gets 6: m 75..80)
    const int bitem = lane >> 4, q = lane & 15;
    const int mstart = (q < 15) ? 5 * q : 75;
    const int mcnt = (q < 15) ? 5 : 6;
    const int nbase = wv * NBW;

    float ya[RMAXA][ITEMS];               // y state, registers, all 100 iters
#pragma unroll
    for (int r = 0; r < RMAXA; ++r)
#pragma unroll
        for (int i = 0; i < ITEMS; ++i) ya[r][i] = 0.f;

    __syncthreads();

    float t = 1.f;
    for (int it = 0; it < NITER; ++it) {
        float tn = (1.f + sqrtf(1.f + t * t)) * 0.5f;
        float coef = (t - 1.f) / tn;
        t = tn;
        const bool last = (it == NITER - 1);

        // ---- Phase A: accA[r][i] = sum_m matT[m][n_r] * z[m][i] ----
        float accA[RMAXA][ITEMS];
#pragma unroll
        for (int r = 0; r < RMAXA; ++r)
#pragma unroll
            for (int i = 0; i < ITEMS; ++i) accA[r][i] = 0.f;

#pragma unroll 3
        for (int m = 0; m < MM; ++m) {
            float4 zv = *(const float4*)&zL[m * ITEMS];      // b128 broadcast
            const float* mtrow = matT + (size_t)m * NN;
#pragma unroll
            for (int r = 0; r < RMAXA; ++r) {
                if (r < rcnt) {                              // wave-uniform
                    float mv = mtrow[r * 1024 + tid];        // coalesced 256B
                    accA[r][0] = fmaf(mv, zv.x, accA[r][0]);
                    accA[r][1] = fmaf(mv, zv.y, accA[r][1]);
                    accA[r][2] = fmaf(mv, zv.z, accA[r][2]);
                    accA[r][3] = fmaf(mv, zv.w, accA[r][3]);
                }
            }
        }

        // ---- y update (regs); publish to yL for Phase B ----
#pragma unroll
        for (int r = 0; r < RMAXA; ++r) {
            if (r < rcnt) {
                int n = r * 1024 + tid;
#pragma unroll
                for (int i = 0; i < ITEMS; ++i) {
                    float yo = ya[r][i];
                    float w  = yo + accA[r][i];                            // MU=1
                    float yn = fmaxf(w - thr, 0.f) + fminf(w + thr, 0.f); // soft-thr
                    float yv = yn + coef * (yn - yo);                      // momentum
                    ya[r][i] = yv;
                    if (!last) yL[i * YPAD + n] = yv;        // conflict-free
                }
            }
        }
        if (last) break;
        __syncthreads();

        // ---- Phase B: lane (item,q) accumulates u[mstart..] over wave's rows ----
        {
            float up[6] = {0.f, 0.f, 0.f, 0.f, 0.f, 0.f};
            const float* ybase = yL + bitem * YPAD;
            for (int k = 0; k < NBW / 4; ++k) {              // 81 steps of 4 rows
                int n = nbase + 4 * k;
                float4 yv = *(const float4*)&ybase[n];       // b128, 4 addrs/wave
#pragma unroll
                for (int j = 0; j < 6; ++j) {
                    if (j < mcnt) {
                        float4 mv = *(const float4*)&matT[(size_t)(mstart + j) * NN + n];
                        up[j] += yv.x * mv.x + yv.y * mv.y + yv.z * mv.z + yv.w * mv.w;
                    }
                }
            }
#pragma unroll
            for (int j = 0; j < 6; ++j)
                if (j < mcnt)                                 // per-lane-distinct addr
                    __hip_atomic_fetch_add(&uL[bitem * UPAD + mstart + j], up[j],
                                           __ATOMIC_RELAXED, __HIP_MEMORY_SCOPE_WORKGROUP);
        }
        __syncthreads();

        // ---- z = x - u (read-then-zero per thread: no race), [m][item] ----
        for (int i = tid; i < MM * ITEMS; i += THREADS) {
            int m = i >> 2, item = i & 3;
            float* up_ = &uL[item * UPAD + m];
            float u = *up_; *up_ = 0.f;
            zL[i] = xL[i] - u;
        }
        __syncthreads();
    }

    // ---- final y -> out (coalesced: lanes -> consecutive n) ----
#pragma unroll
    for (int r = 0; r < RMAXA; ++r) {
        if (r < rcnt) {
            int n = r * 1024 + tid;
#pragma unroll
            for (int i = 0; i < ITEMS; ++i)
                out[(size_t)(b0 + i) * NN + n] = ya[r][i];
        }
    }
}

extern "C" void kernel_launch(void* const* d_in, const int* in_sizes, int n_in,
                              void* d_out, int out_size, void* d_ws, size_t ws_size,
                              hipStream_t stream) {
    const float* x   = (const float*)d_in[0];   // [512][81]
    const float* mat = (const float*)d_in[1];   // [5184][81]
    const float* lam = (const float*)d_in[2];   // [1]
    float* out = (float*)d_out;                 // [512][5184]

    float* matT = (float*)d_ws;                 // [81][5184] = 1.68 MB

    hipFuncSetAttribute((const void*)fista,
                        hipFuncAttributeMaxDynamicSharedMemorySize, LDS_BYTES);
    prep<<<(NN * MM + 255) / 256, 256, 0, stream>>>(mat, matT);
    fista<<<NWG, THREADS, LDS_BYTES, stream>>>(x, lam, matT, out);
}

// Round 10
// 19855.069 us; speedup vs baseline: 1.0163x; 1.0163x over previous
//
#include <hip/hip_runtime.h>
#include <math.h>

#define NN 5184
#define MM 81
#define BTOT 512
#define NITER 100
#define ITEMS 4
#define THREADS 1024
#define NWG (BTOT/ITEMS)      // 128 fully independent workgroups
#define YPAD 5188             // y item stride (5188%32=4 -> staggered banks)
#define UPAD 88
#define NBW 324               // rows per wave in Phase B (5184/16)
#define TAILT 272             // threads owning a second row-group (1088/4)
// LDS: yL[4][5188] + zL[81][4] + xL[81][4] + uL[4][88]
#define LDS_FLOATS (ITEMS*YPAD + MM*ITEMS*2 + ITEMS*UPAD)
#define LDS_BYTES (LDS_FLOATS*4)   // 87,008 B

// d_ws: matT[81][5184] fp32 = 1.68 MB

__global__ void prep(const float* __restrict__ mat, float* __restrict__ matT) {
    int i = blockIdx.x * 256 + threadIdx.x;     // over NN*MM
    if (i >= NN * MM) return;
    int n = i / MM, m = i - n * MM;
    matT[(size_t)m * NN + n] = mat[i];
}

#define FMAROW(accr, mc, zv)                  \
    accr[0] = fmaf(mc, zv.x, accr[0]);        \
    accr[1] = fmaf(mc, zv.y, accr[1]);        \
    accr[2] = fmaf(mc, zv.z, accr[2]);        \
    accr[3] = fmaf(mc, zv.w, accr[3]);

__global__ __launch_bounds__(THREADS) void fista(
        const float* __restrict__ x, const float* __restrict__ lam,
        const float* __restrict__ matT, float* __restrict__ out) {
    extern __shared__ float sm[];
    float* yL = sm;                       // [ITEMS][YPAD]
    float* zL = sm + ITEMS * YPAD;        // [MM][ITEMS]
    float* xL = zL + MM * ITEMS;          // [MM][ITEMS]
    float* uL = xL + MM * ITEMS;          // [ITEMS][UPAD]

    const int tid = threadIdx.x;
    const int wv = tid >> 6, lane = tid & 63;
    const int b0 = blockIdx.x * ITEMS;
    const float thr = lam[0];             // lam / MU, MU = 1

    // ---- init: xL/zL = x (transposed [m][item]), uL = 0 ----
    for (int i = tid; i < MM * ITEMS; i += THREADS) {
        int m = i >> 2, item = i & 3;
        float v = x[(size_t)(b0 + item) * MM + m];
        xL[i] = v; zL[i] = v;
    }
    for (int i = tid; i < ITEMS * UPAD; i += THREADS) uL[i] = 0.f;

    // Phase A ownership: group0 rows 4*tid..+3; group1 rows 4096+4*tid..+3 (tid<272)
    const int c0 = 4 * tid;
    const int c1 = 4096 + 4 * tid;
    const bool has1 = (tid < TAILT);

    // Phase B lane mapping: item x m-quintet (q=15 -> m 75..80)
    const int bitem = lane >> 4, q = lane & 15;
    const int mstart = (q < 15) ? 5 * q : 75;
    const int mcnt = (q < 15) ? 5 : 6;
    const int nbase = wv * NBW;

    float ya0[4][4], ya1[4][4];           // y state (regs, all 100 iters)
#pragma unroll
    for (int r = 0; r < 4; ++r)
#pragma unroll
        for (int i = 0; i < 4; ++i) { ya0[r][i] = 0.f; ya1[r][i] = 0.f; }

    __syncthreads();

    float t = 1.f;
    for (int it = 0; it < NITER; ++it) {
        float tn = (1.f + sqrtf(1.f + t * t)) * 0.5f;
        float coef = (t - 1.f) / tn;
        t = tn;
        const bool last = (it == NITER - 1);

        // ==== Phase A: acc[g][r][i] = sum_m matT[m][row] * z[m][i] ====
        float acc0[4][4] = {{0.f,0.f,0.f,0.f},{0.f,0.f,0.f,0.f},
                            {0.f,0.f,0.f,0.f},{0.f,0.f,0.f,0.f}};
        float acc1[4][4] = {{0.f,0.f,0.f,0.f},{0.f,0.f,0.f,0.f},
                            {0.f,0.f,0.f,0.f},{0.f,0.f,0.f,0.f}};
        {
            float4 zv  = *(const float4*)&zL[0];
            float4 m0v = *(const float4*)(matT + c0);
            float4 m1v = {0.f,0.f,0.f,0.f};
            if (has1) m1v = *(const float4*)(matT + c1);

            for (int m = 0; m < MM; ++m) {
                float4 zn = {0.f,0.f,0.f,0.f};
                float4 m0n = zn, m1n = zn;
                const bool more = (m + 1 < MM);
                if (more) {                       // prefetch m+1 before m's FMAs
                    const float* nr = matT + (size_t)(m + 1) * NN;
                    zn  = *(const float4*)&zL[(m + 1) * ITEMS];
                    m0n = *(const float4*)(nr + c0);
                    if (has1) m1n = *(const float4*)(nr + c1);
                }
                FMAROW(acc0[0], m0v.x, zv)
                FMAROW(acc0[1], m0v.y, zv)
                FMAROW(acc0[2], m0v.z, zv)
                FMAROW(acc0[3], m0v.w, zv)
                if (has1) {
                    FMAROW(acc1[0], m1v.x, zv)
                    FMAROW(acc1[1], m1v.y, zv)
                    FMAROW(acc1[2], m1v.z, zv)
                    FMAROW(acc1[3], m1v.w, zv)
                }
                zv = zn; m0v = m0n; m1v = m1n;
            }
        }

        // ==== y update (regs); publish float4 per item to yL ====
#pragma unroll
        for (int i = 0; i < 4; ++i) {
            float4 yv4;
            float* yv = (float*)&yv4;
#pragma unroll
            for (int r = 0; r < 4; ++r) {
                float yo = ya0[r][i];
                float w  = yo + acc0[r][i];                            // MU=1
                float yn = fmaxf(w - thr, 0.f) + fminf(w + thr, 0.f); // soft-thr
                float v  = yn + coef * (yn - yo);                      // momentum
                ya0[r][i] = v; yv[r] = v;
            }
            if (!last) *(float4*)&yL[i * YPAD + c0] = yv4;
        }
        if (has1) {
#pragma unroll
            for (int i = 0; i < 4; ++i) {
                float4 yv4;
                float* yv = (float*)&yv4;
#pragma unroll
                for (int r = 0; r < 4; ++r) {
                    float yo = ya1[r][i];
                    float w  = yo + acc1[r][i];
                    float yn = fmaxf(w - thr, 0.f) + fminf(w + thr, 0.f);
                    float v  = yn + coef * (yn - yo);
                    ya1[r][i] = v; yv[r] = v;
                }
                if (!last) *(float4*)&yL[i * YPAD + c1] = yv4;
            }
        }
        if (last) break;
        __syncthreads();

        // ==== Phase B: lane (item,q) accumulates u[mstart..] over wave's rows ====
        {
            float up[6] = {0.f, 0.f, 0.f, 0.f, 0.f, 0.f};
            const float* ybase = yL + bitem * YPAD;
#pragma unroll 2
            for (int k = 0; k < NBW / 4; ++k) {              // 81 steps of 4 rows
                int n = nbase + 4 * k;
                float4 yv = *(const float4*)&ybase[n];       // b128 broadcast
#pragma unroll
                for (int j = 0; j < 6; ++j) {
                    if (j < mcnt) {
                        float4 mv = *(const float4*)&matT[(size_t)(mstart + j) * NN + n];
                        up[j] = fmaf(yv.x, mv.x, up[j]);
                        up[j] = fmaf(yv.y, mv.y, up[j]);
                        up[j] = fmaf(yv.z, mv.z, up[j]);
                        up[j] = fmaf(yv.w, mv.w, up[j]);
                    }
                }
            }
#pragma unroll
            for (int j = 0; j < 6; ++j)
                if (j < mcnt)                                 // per-lane-distinct addr
                    __hip_atomic_fetch_add(&uL[bitem * UPAD + mstart + j], up[j],
                                           __ATOMIC_RELAXED, __HIP_MEMORY_SCOPE_WORKGROUP);
        }
        __syncthreads();

        // ==== z = x - u (read-then-zero; no race), [m][item] ====
        for (int i = tid; i < MM * ITEMS; i += THREADS) {
            int m = i >> 2, item = i & 3;
            float* up_ = &uL[item * UPAD + m];
            float u = *up_; *up_ = 0.f;
            zL[i] = xL[i] - u;
        }
        __syncthreads();
    }

    // ==== final y -> out (float4 stores, rows contiguous) ====
#pragma unroll
    for (int i = 0; i < 4; ++i) {
        float4 v0 = {ya0[0][i], ya0[1][i], ya0[2][i], ya0[3][i]};
        *(float4*)&out[(size_t)(b0 + i) * NN + c0] = v0;
    }
    if (has1) {
#pragma unroll
        for (int i = 0; i < 4; ++i) {
            float4 v1 = {ya1[0][i], ya1[1][i], ya1[2][i], ya1[3][i]};
            *(float4*)&out[(size_t)(b0 + i) * NN + c1] = v1;
        }
    }
}

extern "C" void kernel_launch(void* const* d_in, const int* in_sizes, int n_in,
                              void* d_out, int out_size, void* d_ws, size_t ws_size,
                              hipStream_t stream) {
    const float* x   = (const float*)d_in[0];   // [512][81]
    const float* mat = (const float*)d_in[1];   // [5184][81]
    const float* lam = (const float*)d_in[2];   // [1]
    float* out = (float*)d_out;                 // [512][5184]

    float* matT = (float*)d_ws;                 // [81][5184] = 1.68 MB

    hipFuncSetAttribute((const void*)fista,
                        hipFuncAttributeMaxDynamicSharedMemorySize, LDS_BYTES);
    prep<<<(NN * MM + 255) / 256, 256, 0, stream>>>(mat, matT);
    fista<<<NWG, THREADS, LDS_BYTES, stream>>>(x, lam, matT, out);
}